// Round 2
// baseline (175.986 us; speedup 1.0000x reference)
//
#include <hip/hip_runtime.h>
#include <hip/hip_bf16.h>

// Problem constants (fixed by the reference)
#define BB 1024
#define LL 256
#define DD 64
#define TDIM 100

typedef _Float16 half8_t __attribute__((ext_vector_type(8)));
typedef float f32x4 __attribute__((ext_vector_type(4)));

// One block = one (batch row, side) pair. side 0 -> src features, 1 -> dst.
// Threads: 256 (4 waves). Thread t owns position t of the row:
//   counts -> time weight -> g[64] (fp16, into LDS in MFMA A-fragment order)
// then the 4 waves run a 256x64x64 GEMM tile with v_mfma_f32_16x16x32_f16.
// ALL float tensors are fp32 (reference is jnp.float32 throughout); round-0
// bf16 casts produced NaN (fp32 low-mantissa halves decode as bf16 NaNs).
__global__ __launch_bounds__(256, 2) void tni_kernel(
    const int* __restrict__ src_ids, const int* __restrict__ dst_ids,
    const float* __restrict__ src_tm, const float* __restrict__ dst_tm,
    const float* __restrict__ node_tm,
    const float* __restrict__ w_time, const float* __restrict__ b_time,
    const float* __restrict__ w_ts, const float* __restrict__ b_ts,
    const float* __restrict__ w1, const float* __restrict__ b1,
    const float* __restrict__ w2, const float* __restrict__ b2,
    float* __restrict__ out)
{
    __shared__ int4 ids_s4[LL/4];          // src id row
    __shared__ int4 ids_d4[LL/4];          // dst id row
    __shared__ float wrv[TDIM], brv[TDIM], wtsv[TDIM]; // time-encoder coeffs (pre-scaled to revolutions)
    __shared__ float w1v[DD], b1v[DD];
    __shared__ half8_t W2v[DD*8];          // w2^T rows (B-fragment order), XOR-swizzled 16B chunks
    __shared__ half8_t Gv[LL*8];           // g rows (A-fragment order), XOR-swizzled 16B chunks

    const int t    = threadIdx.x;
    const int b    = blockIdx.x >> 1;
    const int side = blockIdx.x & 1;

    // ---- stage inputs into LDS ----
    ((int*)ids_s4)[t] = src_ids[b*LL + t];
    ((int*)ids_d4)[t] = dst_ids[b*LL + t];
    if (t < TDIM) {
        const float inv2pi = 0.15915494309189535f;   // v_cos_f32 takes revolutions
        wrv[t]  = w_time[t] * inv2pi;
        brv[t]  = b_time[t] * inv2pi;
        wtsv[t] = w_ts[t];
    }
    if (t < DD) {
        w1v[t] = w1[t];
        b1v[t] = b1[t];
    }
    {   // w2 (row-major [e][d], fp32) -> W2v = w2^T rows [d][e] as fp16, swizzled
        _Float16* w2s = (_Float16*)W2v;
        #pragma unroll
        for (int i = 0; i < 16; ++i) {
            int idx = t + 256*i;            // 0..4095
            int e = idx >> 6, d = idx & 63;
            int chunk = (e >> 3) ^ (d & 7); // XOR swizzle on 16B chunks within a row
            w2s[d*64 + (chunk << 3) + (e & 7)] = (_Float16)w2[idx];
        }
    }
    __syncthreads();

    // ---- counts: matches of my id in src row (c1) and dst row (c2) ----
    const int   my_id = side ? ((const int*)ids_d4)[t] : ((const int*)ids_s4)[t];
    const float my_tm = side ? dst_tm[b*LL + t] : src_tm[b*LL + t];

    int c1 = 0, c2 = 0;
    #pragma unroll 4
    for (int j = 0; j < LL/4; ++j) {
        int4 a  = ids_s4[j];
        int4 dd = ids_d4[j];
        c1 += (a.x==my_id) + (a.y==my_id) + (a.z==my_id) + (a.w==my_id);
        c2 += (dd.x==my_id) + (dd.y==my_id) + (dd.z==my_id) + (dd.w==my_id);
    }
    if (my_id == 0) { c1 = 0; c2 = 0; }   // padding id -> zero count (mask semantics)

    // ---- time weight: sigmoid(cos(td*w+b) @ w_ts + b_ts) ----
    float td = node_tm[b] - my_tm;
    float z  = b_ts[0];
    #pragma unroll 4
    for (int k = 0; k < TDIM; ++k) {
        float r = fmaf(td, wrv[k], brv[k]);
        r -= floorf(r);                               // reduce to [0,1) revolutions
        z = fmaf(__builtin_amdgcn_cosf(r), wtsv[k], z);
    }
    float ee  = __builtin_amdgcn_exp2f(-1.44269504f * z);  // exp(-z)
    float wgt = __builtin_amdgcn_rcpf(1.0f + ee);          // sigmoid(z)
    float c1w = (float)c1 * wgt;
    float c2w = (float)c2 * wgt;

    // ---- g[e] = relu(c1w*w1+b1) + relu(c2w*w1+b1), fp16 into A-fragment LDS ----
    #pragma unroll
    for (int c = 0; c < 8; ++c) {
        half8_t h;
        #pragma unroll
        for (int j = 0; j < 8; ++j) {
            float w1e = w1v[c*8 + j], b1e = b1v[c*8 + j];
            float g = fmaxf(fmaf(c1w, w1e, b1e), 0.f)
                    + fmaxf(fmaf(c2w, w1e, b1e), 0.f);
            h[j] = (_Float16)g;
        }
        Gv[t*8 + (c ^ (t & 7))] = h;      // row t, swizzled chunk
    }
    __syncthreads();

    // ---- MFMA: [256 x 64] x [64 x 64], wave w owns rows 64w..64w+63 ----
    const int w    = t >> 6;
    const int l    = t & 63;
    const int quad = l >> 4;
    const int lr   = l & 15;

    f32x4 acc[4][4];
    #pragma unroll
    for (int mt = 0; mt < 4; ++mt)
        #pragma unroll
        for (int nt = 0; nt < 4; ++nt) {
            f32x4 zz = {0.f, 0.f, 0.f, 0.f};
            acc[mt][nt] = zz;
        }

    #pragma unroll
    for (int s = 0; s < 2; ++s) {         // K steps of 32
        const int c = s*4 + quad;         // logical 16B chunk (8 k's) this lane reads
        half8_t bfr[4], afr[4];
        #pragma unroll
        for (int nt = 0; nt < 4; ++nt) {  // B: lane holds B[k=quad*8+j][n=lane&15] = w2T row n
            int n = nt*16 + lr;
            bfr[nt] = W2v[n*8 + (c ^ (n & 7))];
        }
        #pragma unroll
        for (int mt = 0; mt < 4; ++mt) {  // A: lane holds A[m=lane&15][k=quad*8+j]
            int row = w*64 + mt*16 + lr;
            afr[mt] = Gv[row*8 + (c ^ (row & 7))];
        }
        #pragma unroll
        for (int mt = 0; mt < 4; ++mt)
            #pragma unroll
            for (int nt = 0; nt < 4; ++nt)
                acc[mt][nt] = __builtin_amdgcn_mfma_f32_16x16x32_f16(
                    afr[mt], bfr[nt], acc[mt][nt], 0, 0, 0);
    }

    // ---- epilogue: +2*b2, store fp32. C layout: col=lane&15, row=quad*4+reg ----
    float b2v[4];
    #pragma unroll
    for (int nt = 0; nt < 4; ++nt)
        b2v[nt] = 2.f * b2[nt*16 + lr];

    const int obase = side * (BB*LL*DD) + b * (LL*DD);
    #pragma unroll
    for (int mt = 0; mt < 4; ++mt) {
        #pragma unroll
        for (int r = 0; r < 4; ++r) {
            int pos = w*64 + mt*16 + quad*4 + r;
            #pragma unroll
            for (int nt = 0; nt < 4; ++nt) {
                out[obase + pos*DD + nt*16 + lr] = acc[mt][nt][r] + b2v[nt];
            }
        }
    }
}

extern "C" void kernel_launch(void* const* d_in, const int* in_sizes, int n_in,
                              void* d_out, int out_size, void* d_ws, size_t ws_size,
                              hipStream_t stream) {
    const int* src_ids = (const int*)d_in[0];
    const int* dst_ids = (const int*)d_in[1];
    const float* src_tm  = (const float*)d_in[2];
    const float* dst_tm  = (const float*)d_in[3];
    const float* node_tm = (const float*)d_in[4];
    // d_in[5] = num_nodes (unused: counts are computed by direct id comparison)
    const float* w_time = (const float*)d_in[6];
    const float* b_time = (const float*)d_in[7];
    const float* w_ts   = (const float*)d_in[8];
    const float* b_ts   = (const float*)d_in[9];
    const float* w1     = (const float*)d_in[10];
    const float* b1     = (const float*)d_in[11];
    const float* w2     = (const float*)d_in[12];
    const float* b2     = (const float*)d_in[13];
    float* out = (float*)d_out;

    tni_kernel<<<dim3(BB*2), dim3(256), 0, stream>>>(
        src_ids, dst_ids, src_tm, dst_tm, node_tm,
        w_time, b_time, w_ts, b_ts, w1, b1, w2, b2, out);
}